// Round 1
// 135.322 us; speedup vs baseline: 1.0055x; 1.0055x over previous
//
#include <hip/hip_runtime.h>
#include <hip/hip_bf16.h>

// B=16, S=2048, D=128 causal attention, pre-scale threshold:
//   A = Q@T^T; A = (A>0.3 ? A : 0); causal -2^32; /sqrt(128); softmax; @V
// fp32 in/out, bf16 MFMA internal.
// Fixed-max softmax (post-threshold logits in [0,~9], m=0 safe) => partial
// (oacc, sum-l) accumulators combine ADDITIVELY => K-split is trivial.
//
// V2 structure: one 512-thread block per (batch, q-tile-pair (i,31-i)).
//   Pair work = exactly 33 K-tile iterations for every pair => uniform blocks,
//   no triangular drain tail (V1 spent most time at 1 wave/SIMD).
//   group0 (waves 0-3): heavy qtile, K-tiles [0,17)
//   group1 (waves 4-7): light qtile fully ([0,i]), 1 bubble slot (finalize
//                       light), then heavy K-tiles [17,32-i)   => 17 slots each.
//   Heavy partials combined through LDS after the loop (additive).
// LDS: XOR-swizzle (byte ^= (row&7)<<4), unpadded strides -> conflict-free
//   ds_read_b128 fragment reads (V1 had 4.6M conflict-cycles ~12% of kernel).

#define S_LEN 2048
#define D_DIM 128
#define BQ 64
#define BK 64
#define THRESH 0.3f
#define SCALE 0.08838834764831845f   // 1/sqrt(128)

typedef __bf16 bf16x8 __attribute__((ext_vector_type(8)));
typedef float f32x4 __attribute__((ext_vector_type(4)));

// -------- V transpose + downcast: V[b][s][d] fp32 -> Vt[b][d][s] bf16 --------
__global__ void vt_kernel(const float* __restrict__ V, __bf16* __restrict__ Vt) {
    __shared__ float tile[64][65];
    int bid = blockIdx.x;
    int b  = bid >> 6;
    int t2 = bid & 63;
    int s0 = (t2 >> 1) * 64;
    int d0 = (t2 & 1) * 64;
    int tid = threadIdx.x;                     // 256 threads
    #pragma unroll
    for (int it = 0; it < 2; ++it) {
        int row = it * 32 + (tid >> 3);
        int c   = (tid & 7) * 8;
        const float* p = V + ((size_t)b * S_LEN + s0 + row) * D_DIM + d0 + c;
        *(f32x4*)(&tile[row][c])     = *(const f32x4*)p;
        *(f32x4*)(&tile[row][c + 4]) = *(const f32x4*)(p + 4);
    }
    __syncthreads();
    #pragma unroll
    for (int it = 0; it < 2; ++it) {
        int dr = it * 32 + (tid >> 3);
        int c  = (tid & 7) * 8;
        bf16x8 w;
        #pragma unroll
        for (int j = 0; j < 8; ++j) w[j] = (__bf16)tile[c + j][dr];
        *(bf16x8*)(Vt + ((size_t)b * D_DIM + d0 + dr) * S_LEN + s0 + c) = w;
    }
}

// ---------------- Flash attention, causal + threshold, fixed-max ----------------
// LDS map (80 KB):
//   [     0, 16384)  Tt group0: 64 rows x 128 bf16 (256B/row, swizzled)
//   [ 16384, 32768)  Tt group1
//   [ 32768, 49152)  Vl group0: 128 rows x 64 bf16 (128B/row, swizzled)
//   [ 49152, 65536)  Vl group1
//   [ 65536, 81920)  Pl: 8 waves x (16 rows x 64 bf16, 128B/row, swizzled)
// After the slot loop, [0,32768) is reused as f32[64][128] heavy-partial
// combine buffer (512B/row, swizzled) and [65536,65792) as f32[64] partial l.
__global__ __launch_bounds__(512, 2)
void fa_kernel(const float* __restrict__ Q, const float* __restrict__ T,
               const __bf16* __restrict__ Vt, float* __restrict__ O) {
    __shared__ __align__(16) unsigned char smem[81920];

    const int bid = blockIdx.x;
    const int b   = bid & 15;
    const int pi  = bid >> 4;           // pair index 0..15
    const int qtH = 31 - pi;            // heavy q-tile (>=16)
    const int L   = pi + 1;             // light K-tile count (1..16)

    const int tid   = threadIdx.x;
    const int g     = tid >> 8;         // group 0/1
    const int tid_g = tid & 255;
    const int lane  = tid & 63;
    const int wg    = tid >> 6;         // global wave 0..7
    const int wv    = wg & 3;           // wave within group
    const int col   = lane & 15;
    const int quad  = lane >> 4;

    unsigned char* Tt = smem + g * 16384;
    unsigned char* Vl = smem + 32768 + g * 16384;
    unsigned char* Pw = smem + 65536 + wg * 2048;

    // ---- Q fragments (16 rows x D=128), bf16, reloadable (group1 switches) ----
    bf16x8 qf[4];
    auto loadQ = [&](int qt) {
        const float* qptr = Q + ((size_t)b * S_LEN + qt * BQ + wv * 16 + col) * D_DIM + quad * 8;
        #pragma unroll
        for (int kk = 0; kk < 4; ++kk) {
            f32x4 a = *(const f32x4*)(qptr + kk * 32);
            f32x4 c = *(const f32x4*)(qptr + kk * 32 + 4);
            #pragma unroll
            for (int j = 0; j < 4; ++j) { qf[kk][j] = (__bf16)a[j]; qf[kk][4 + j] = (__bf16)c[j]; }
        }
    };

    f32x4 oacc[8];
    float lsum[4];
    auto resetAcc = [&]() {
        #pragma unroll
        for (int dt = 0; dt < 8; ++dt) oacc[dt] = {0.f, 0.f, 0.f, 0.f};
        #pragma unroll
        for (int r = 0; r < 4; ++r) lsum[r] = 0.f;
    };

    // ---- staging: global -> regs -> swizzled LDS (per group, 256 threads) ----
    f32x4 tr[8]; bf16x8 vr[4];
    auto loadTiles = [&](int k0) {
        #pragma unroll
        for (int it = 0; it < 4; ++it) {
            int flat = it * 2048 + tid_g * 8;
            int row = flat >> 7, c = flat & 127;
            const float* p = T + ((size_t)b * S_LEN + k0 + row) * D_DIM + c;
            tr[2 * it]     = *(const f32x4*)p;
            tr[2 * it + 1] = *(const f32x4*)(p + 4);
        }
        #pragma unroll
        for (int it = 0; it < 4; ++it) {
            int flat = it * 2048 + tid_g * 8;
            int d = flat >> 6, kk2 = flat & 63;
            vr[it] = *(const bf16x8*)(Vt + ((size_t)b * D_DIM + d) * S_LEN + k0 + kk2);
        }
    };
    auto storeTiles = [&]() {
        #pragma unroll
        for (int it = 0; it < 4; ++it) {
            int flat = it * 2048 + tid_g * 8;
            int row = flat >> 7, c = flat & 127;
            bf16x8 w;
            #pragma unroll
            for (int j = 0; j < 4; ++j) {
                w[j]     = (__bf16)tr[2 * it][j];
                w[4 + j] = (__bf16)tr[2 * it + 1][j];
            }
            *(bf16x8*)(Tt + row * 256 + ((c * 2) ^ ((row & 7) << 4))) = w;
        }
        #pragma unroll
        for (int it = 0; it < 4; ++it) {
            int flat = it * 2048 + tid_g * 8;
            int d = flat >> 6, kk2 = flat & 63;
            *(bf16x8*)(Vl + d * 128 + ((kk2 * 2) ^ ((d & 7) << 4))) = vr[it];
        }
    };

    // ---- one K-tile: QK^T -> threshold/exp -> P relayout -> PV ----
    auto computeTile = [&](bool diag) {
        f32x4 sacc[4];
        #pragma unroll
        for (int t = 0; t < 4; ++t) {
            sacc[t] = {0.f, 0.f, 0.f, 0.f};
            #pragma unroll
            for (int kk = 0; kk < 4; ++kk) {
                int row = t * 16 + col;
                bf16x8 bf = *(const bf16x8*)(Tt + row * 256 + ((kk * 64 + quad * 16) ^ ((row & 7) << 4)));
                sacc[t] = __builtin_amdgcn_mfma_f32_16x16x32_bf16(qf[kk], bf, sacc[t], 0, 0, 0);
            }
        }
        float p[4][4];
        #pragma unroll
        for (int t = 0; t < 4; ++t)
            #pragma unroll
            for (int r = 0; r < 4; ++r) {
                float s = sacc[t][r];
                float e = __expf(s * SCALE);
                float w = (s > THRESH) ? e : 1.0f;
                if (diag && (t * 16 + col > wv * 16 + quad * 4 + r)) w = 0.0f;
                p[t][r] = w;
            }
        #pragma unroll
        for (int r = 0; r < 4; ++r)
            lsum[r] += (p[0][r] + p[1][r]) + (p[2][r] + p[3][r]);

        // C-layout -> LDS -> A-layout (per-wave scratch, swizzled)
        #pragma unroll
        for (int t = 0; t < 4; ++t)
            #pragma unroll
            for (int r = 0; r < 4; ++r) {
                int row = quad * 4 + r;
                *(__bf16*)(Pw + row * 128 + (((t * 16 + col) * 2) ^ ((row & 7) << 4))) = (__bf16)p[t][r];
            }
        asm volatile("s_waitcnt lgkmcnt(0)" ::: "memory");  // wave-local RAW on Pw

        #pragma unroll
        for (int ks = 0; ks < 2; ++ks) {
            bf16x8 af = *(const bf16x8*)(Pw + col * 128 + ((ks * 64 + quad * 16) ^ ((col & 7) << 4)));
            #pragma unroll
            for (int dt = 0; dt < 8; ++dt) {
                int row = dt * 16 + col;
                bf16x8 bf = *(const bf16x8*)(Vl + row * 128 + ((ks * 64 + quad * 16) ^ ((row & 7) << 4)));
                oacc[dt] = __builtin_amdgcn_mfma_f32_16x16x32_bf16(af, bf, oacc[dt], 0, 0, 0);
            }
        }
    };

    // slot -> K-tile id (-1 = no tile: group1 bubble, or past end)
    auto slotKT = [&](int s) -> int {
        if (s >= 17) return -1;
        if (g == 0) return s;              // heavy [0,17)
        if (s < L)  return s;              // light [0,L)
        if (s == L) return -1;             // bubble
        return s + 15 - pi;                // heavy [17, 32-pi)
    };

    resetAcc();
    int qtile = (g == 0) ? qtH : pi;
    loadQ(qtile);

    // prologue: slot-0 tile (kt=0 for both groups)
    loadTiles(0);
    storeTiles();
    __syncthreads();

    for (int s = 0; s < 17; ++s) {
        int kt  = slotKT(s);
        int ktn = slotKT(s + 1);
        if (ktn >= 0) loadTiles(ktn * BK);   // prefetch into regs
        if (kt >= 0) {
            computeTile(kt == qtile);
        } else {
            // group1 bubble: finalize + store light q-tile, switch to heavy
            float inv[4];
            #pragma unroll
            for (int r = 0; r < 4; ++r) {
                float l = lsum[r];
                l += __shfl_xor(l, 1); l += __shfl_xor(l, 2);
                l += __shfl_xor(l, 4); l += __shfl_xor(l, 8);
                inv[r] = 1.0f / l;           // diagonal key contributes >=1
            }
            float* optr = O + ((size_t)b * S_LEN + (size_t)pi * BQ + wv * 16) * D_DIM;
            #pragma unroll
            for (int dt = 0; dt < 8; ++dt)
                #pragma unroll
                for (int r = 0; r < 4; ++r)
                    optr[(quad * 4 + r) * D_DIM + dt * 16 + col] = oacc[dt][r] * inv[r];
            resetAcc();
            qtile = qtH;
            loadQ(qtH);
        }
        __syncthreads();                     // tile consumed by this group
        if (ktn >= 0) storeTiles();          // regs -> LDS (waits vmcnt here)
        __syncthreads();                     // next tile visible
    }

    // ---- heavy-q-tile combine: group1 partial + group0 partial (additive) ----
    float lred[4];
    #pragma unroll
    for (int r = 0; r < 4; ++r) {
        float l = lsum[r];
        l += __shfl_xor(l, 1); l += __shfl_xor(l, 2);
        l += __shfl_xor(l, 4); l += __shfl_xor(l, 8);
        lred[r] = l;
    }

    if (g == 1) {
        #pragma unroll
        for (int dt = 0; dt < 8; ++dt)
            #pragma unroll
            for (int r = 0; r < 4; ++r) {
                int row = wv * 16 + quad * 4 + r;
                *(float*)(smem + row * 512 + (((dt * 16 + col) * 4) ^ ((row & 7) << 4))) = oacc[dt][r];
            }
        if (col == 0) {
            #pragma unroll
            for (int r = 0; r < 4; ++r)
                *(float*)(smem + 65536 + (wv * 16 + quad * 4 + r) * 4) = lred[r];
        }
    }
    __syncthreads();
    if (g == 0) {
        float inv[4];
        #pragma unroll
        for (int r = 0; r < 4; ++r) {
            int row = wv * 16 + quad * 4 + r;
            float lp = *(const float*)(smem + 65536 + row * 4);
            inv[r] = 1.0f / (lred[r] + lp);
        }
        float* optr = O + ((size_t)b * S_LEN + (size_t)qtH * BQ + wv * 16) * D_DIM;
        #pragma unroll
        for (int dt = 0; dt < 8; ++dt)
            #pragma unroll
            for (int r = 0; r < 4; ++r) {
                int row = wv * 16 + quad * 4 + r;
                float part = *(const float*)(smem + row * 512 + (((dt * 16 + col) * 4) ^ ((row & 7) << 4)));
                optr[(quad * 4 + r) * D_DIM + dt * 16 + col] = (oacc[dt][r] + part) * inv[r];
            }
    }
}

extern "C" void kernel_launch(void* const* d_in, const int* in_sizes, int n_in,
                              void* d_out, int out_size, void* d_ws, size_t ws_size,
                              hipStream_t stream) {
    const float* Q = (const float*)d_in[0];
    const float* T = (const float*)d_in[1];
    const float* V = (const float*)d_in[2];
    __bf16* Vt = (__bf16*)d_ws;               // 16*128*2048*2 = 8 MB scratch
    float* O   = (float*)d_out;

    vt_kernel<<<16 * 64, 256, 0, stream>>>(V, Vt);
    fa_kernel<<<16 * 16, 512, 0, stream>>>(Q, T, Vt, O);
}